// Round 1
// baseline (1186.831 us; speedup 1.0000x reference)
//
#include <hip/hip_runtime.h>
#include <stdint.h>

#define S_ 2048
#define H_ 16
#define DH_ 128
#define DM_ 2048
#define MROWS 4096   // B*S

typedef unsigned short u16;
typedef _Float16 f16x8 __attribute__((ext_vector_type(8)));
typedef float f32x4 __attribute__((ext_vector_type(4)));

__device__ __forceinline__ void gload16(const void* g, void* l) {
  __builtin_amdgcn_global_load_lds(
      (const __attribute__((address_space(1))) unsigned int*)g,
      (__attribute__((address_space(3))) unsigned int*)l, 16, 0, 0);
}

__device__ __forceinline__ u16 f2h(float f) {
  return __builtin_bit_cast(u16, (_Float16)f);
}

// ---------------- conversion kernels ----------------
__global__ void cvt_hi_k(const float* __restrict__ s, u16* __restrict__ dh, int n4) {
  int i = blockIdx.x * blockDim.x + threadIdx.x;
  const int st = gridDim.x * blockDim.x;
  for (; i < n4; i += st) {
    const float4 v = reinterpret_cast<const float4*>(s)[i];
    ushort4 h;
    h.x = f2h(v.x); h.y = f2h(v.y); h.z = f2h(v.z); h.w = f2h(v.w);
    reinterpret_cast<ushort4*>(dh)[i] = h;
  }
}

__global__ void cvt_split_k(const float* __restrict__ s, u16* __restrict__ dh,
                            u16* __restrict__ dl, int n4) {
  int i = blockIdx.x * blockDim.x + threadIdx.x;
  const int st = gridDim.x * blockDim.x;
  for (; i < n4; i += st) {
    const float4 v = reinterpret_cast<const float4*>(s)[i];
    ushort4 h, l;
    _Float16 b; float f;
    b = (_Float16)v.x; f = (float)b; h.x = __builtin_bit_cast(u16, b); l.x = f2h(v.x - f);
    b = (_Float16)v.y; f = (float)b; h.y = __builtin_bit_cast(u16, b); l.y = f2h(v.y - f);
    b = (_Float16)v.z; f = (float)b; h.z = __builtin_bit_cast(u16, b); l.z = f2h(v.z - f);
    b = (_Float16)v.w; f = (float)b; h.w = __builtin_bit_cast(u16, b); l.w = f2h(v.w - f);
    reinterpret_cast<ushort4*>(dh)[i] = h;
    reinterpret_cast<ushort4*>(dl)[i] = l;
  }
}

// cos/sin tables [S][64], f32, angle product done in f32 to mirror reference rounding
__global__ void rope_tab_k(const int* __restrict__ pos, float* __restrict__ ct,
                           float* __restrict__ st) {
  const int s = blockIdx.x, i = threadIdx.x;   // 64 threads
  const double invd = exp((double)i * (-9.210340371976184 / 64.0));
  const float a = (float)pos[s] * (float)invd;  // f32 RNE product like reference
  ct[(s << 6) + i] = (float)cos((double)a);
  st[(s << 6) + i] = (float)sin((double)a);
}

// ---------------- GEMM: out[m,n] = sum_k A[m,k]*B[n,k] ----------------
// MODE 0: plain f16 in -> f16 out (V proj)
// MODE 1: split f16 hi/lo in (3 mfma) -> RoPE epilogue -> dual f16 hi/lo out (Q,K proj)
// MODE 2: plain f16 in -> f32 out (O proj -> d_out)
template<int MODE>
__global__ __launch_bounds__(256)
void gemm_k(const u16* __restrict__ Ah, const u16* __restrict__ Al,
            const u16* __restrict__ Bh, const u16* __restrict__ Bl,
            void* __restrict__ C0, void* __restrict__ C1,
            const float* __restrict__ ct, const float* __restrict__ st,
            const int Nn, const int Kk) {
  constexpr int NB = (MODE == 1) ? 2 : 1;
  __shared__ __align__(16) u16 As[NB][4096];   // [128][32]
  __shared__ __align__(16) u16 Bs[NB][4096];
  const int tid = threadIdx.x;
  const int wid = tid >> 6, lane = tid & 63;
  const int c16 = lane & 15, hi = lane >> 4;
  const int nbn = Nn >> 7;
  const int bm = (int)blockIdx.x / nbn;
  const int bn = (int)blockIdx.x - bm * nbn;
  const int m0 = bm << 7, n0 = bn << 7;
  const int wm = (wid >> 1) << 6, wn = (wid & 1) << 6;

  f32x4 acc[4][4] = {};
  const int nk = Kk >> 5;
  for (int kt = 0; kt < nk; ++kt) {
    const int k0 = kt << 5;
    __syncthreads();
#pragma unroll
    for (int rep = 0; rep < 2; ++rep) {
      const int cw = wid + (rep << 2);
      const int c = (cw << 6) + lane;
      const size_t aoff = (size_t)(m0 + (c >> 2)) * Kk + k0 + ((c & 3) << 3);
      const size_t boff = (size_t)(n0 + (c >> 2)) * Kk + k0 + ((c & 3) << 3);
      gload16(Ah + aoff, &As[0][cw << 9]);
      gload16(Bh + boff, &Bs[0][cw << 9]);
      if constexpr (MODE == 1) {
        gload16(Al + aoff, &As[1][cw << 9]);
        gload16(Bl + boff, &Bs[1][cw << 9]);
      }
    }
    __syncthreads();
    f16x8 afh[4], bfh[4];
#pragma unroll
    for (int i = 0; i < 4; ++i) {
      afh[i] = *reinterpret_cast<const f16x8*>(&As[0][((wm + (i << 4) + c16) << 5) + (hi << 3)]);
      bfh[i] = *reinterpret_cast<const f16x8*>(&Bs[0][((wn + (i << 4) + c16) << 5) + (hi << 3)]);
    }
    if constexpr (MODE == 1) {
      f16x8 afl[4], bfl[4];
#pragma unroll
      for (int i = 0; i < 4; ++i) {
        afl[i] = *reinterpret_cast<const f16x8*>(&As[1][((wm + (i << 4) + c16) << 5) + (hi << 3)]);
        bfl[i] = *reinterpret_cast<const f16x8*>(&Bs[1][((wn + (i << 4) + c16) << 5) + (hi << 3)]);
      }
#pragma unroll
      for (int i = 0; i < 4; ++i)
#pragma unroll
        for (int j = 0; j < 4; ++j) {
          acc[i][j] = __builtin_amdgcn_mfma_f32_16x16x32_f16(afh[i], bfh[j], acc[i][j], 0, 0, 0);
          acc[i][j] = __builtin_amdgcn_mfma_f32_16x16x32_f16(afh[i], bfl[j], acc[i][j], 0, 0, 0);
          acc[i][j] = __builtin_amdgcn_mfma_f32_16x16x32_f16(afl[i], bfh[j], acc[i][j], 0, 0, 0);
        }
    } else {
#pragma unroll
      for (int i = 0; i < 4; ++i)
#pragma unroll
        for (int j = 0; j < 4; ++j)
          acc[i][j] = __builtin_amdgcn_mfma_f32_16x16x32_f16(afh[i], bfh[j], acc[i][j], 0, 0, 0);
    }
  }
  const int rbase = m0 + wm + (hi << 2);
  const int cbase = n0 + wn + c16;
  if constexpr (MODE == 2) {
    float* C = (float*)C0;
#pragma unroll
    for (int i = 0; i < 4; ++i)
#pragma unroll
      for (int j = 0; j < 4; ++j)
#pragma unroll
        for (int e = 0; e < 4; ++e)
          C[(size_t)(rbase + (i << 4) + e) * Nn + cbase + (j << 4)] = acc[i][j][e];
  } else if constexpr (MODE == 0) {
    u16* C = (u16*)C0;
#pragma unroll
    for (int i = 0; i < 4; ++i)
#pragma unroll
      for (int j = 0; j < 4; ++j)
#pragma unroll
        for (int e = 0; e < 4; ++e)
          C[(size_t)(rbase + (i << 4) + e) * Nn + cbase + (j << 4)] = f2h(acc[i][j][e]);
  } else {
    // MODE 1: RoPE (pair exchange across adjacent lanes) + hi/lo split write
    u16* Ch = (u16*)C0;
    u16* Cl = (u16*)C1;
    const bool even = ((c16 & 1) == 0);
#pragma unroll
    for (int j = 0; j < 4; ++j) {
      const int n = cbase + (j << 4);
      const int fi = (n & 127) >> 1;
#pragma unroll
      for (int i = 0; i < 4; ++i)
#pragma unroll
        for (int e = 0; e < 4; ++e) {
          const int r = rbase + (i << 4) + e;
          const int s = r & (S_ - 1);
          const float cz = ct[(s << 6) + fi];
          const float sz = st[(s << 6) + fi];
          const float v = acc[i][j][e];
          const float other = __shfl_xor(v, 1);
          const float res = even ? (v * cz - other * sz) : (other * sz + v * cz);
          const _Float16 hb = (_Float16)res;
          const size_t off = (size_t)r * Nn + n;
          Ch[off] = __builtin_bit_cast(u16, hb);
          Cl[off] = f2h(res - (float)hb);
        }
    }
  }
}

// ---------------- V transpose: [B,S,H,Dh] -> [B,H,Dh,S] ----------------
__global__ __launch_bounds__(256)
void transv_k(const u16* __restrict__ V, u16* __restrict__ Vt) {
  __shared__ u16 tile[64][65];
  const int bid = blockIdx.x;          // B*H*32*2 = 2048
  const int dblk = bid & 1;
  const int sblk = (bid >> 1) & 31;
  const int bh = bid >> 6;             // 0..31
  const int b = bh >> 4, h = bh & 15;
  const int s0 = sblk << 6, d0 = dblk << 6;
  const int col = threadIdx.x & 63, rb = threadIdx.x >> 6;
#pragma unroll
  for (int i = 0; i < 16; ++i) {
    const int r = (i << 2) + rb;
    tile[r][col] = V[(size_t)(b * S_ + s0 + r) * DM_ + h * DH_ + d0 + col];
  }
  __syncthreads();
#pragma unroll
  for (int i = 0; i < 16; ++i) {
    const int d = (i << 2) + rb;
    Vt[(size_t)(bh * DH_ + d0 + d) * S_ + s0 + col] = tile[col][d];
  }
}

// ---------------- flash attention, causal, split-f16 QK^T ----------------
__global__ __launch_bounds__(256)
void attn_k(const u16* __restrict__ Qh, const u16* __restrict__ Ql,
            const u16* __restrict__ Kh, const u16* __restrict__ Kl,
            const u16* __restrict__ Vt, u16* __restrict__ O) {
  __shared__ __align__(16) u16 Pl[4][1024];    // per-wave 16x64 P tile, XOR-swizzled
  const int bid = blockIdx.x;                  // B*H*32 = 1024
  const int qt = bid & 31;
  const int h = (bid >> 5) & 15;
  const int b = bid >> 9;
  const int bh = (b << 4) + h;
  const int q0 = qt << 6;
  const int tid = threadIdx.x;
  const int wid = tid >> 6, lane = tid & 63;
  const int c16 = lane & 15, hi = lane >> 4;

  const size_t qoff = (size_t)(b * S_ + q0 + (wid << 4) + c16) * DM_ + h * DH_;
  f16x8 qfh[4], qfl[4];
#pragma unroll
  for (int dc = 0; dc < 4; ++dc) {
    qfh[dc] = *reinterpret_cast<const f16x8*>(Qh + qoff + (dc << 5) + (hi << 3));
    qfl[dc] = *reinterpret_cast<const f16x8*>(Ql + qoff + (dc << 5) + (hi << 3));
  }

  float mrow[4], lsum[4];
#pragma unroll
  for (int j = 0; j < 4; ++j) { mrow[j] = -__builtin_inff(); lsum[j] = 0.f; }
  f32x4 oacc[8] = {};

  const size_t kb0 = (size_t)(b * S_) * DM_ + h * DH_;
  const size_t vb0 = (size_t)bh * DH_ * S_;
  char* pw = (char*)&Pl[wid][0];

  for (int kt = 0; kt <= qt; ++kt) {           // uniform trip count per block
    const int kv0 = kt << 6;
    f32x4 sacc[4] = {};
#pragma unroll
    for (int ni = 0; ni < 4; ++ni) {
      const size_t ko = kb0 + (size_t)(kv0 + (ni << 4) + c16) * DM_ + (hi << 3);
#pragma unroll
      for (int dc = 0; dc < 4; ++dc) {
        const f16x8 kfh = *reinterpret_cast<const f16x8*>(Kh + ko + (dc << 5));
        const f16x8 kfl = *reinterpret_cast<const f16x8*>(Kl + ko + (dc << 5));
        sacc[ni] = __builtin_amdgcn_mfma_f32_16x16x32_f16(qfh[dc], kfh, sacc[ni], 0, 0, 0);
        sacc[ni] = __builtin_amdgcn_mfma_f32_16x16x32_f16(qfh[dc], kfl, sacc[ni], 0, 0, 0);
        sacc[ni] = __builtin_amdgcn_mfma_f32_16x16x32_f16(qfl[dc], kfh, sacc[ni], 0, 0, 0);
      }
    }
    // scale + causal mask + online softmax (rows live in 16-lane groups)
#pragma unroll
    for (int j = 0; j < 4; ++j) {
      const int qg = q0 + (wid << 4) + (hi << 2) + j;
      float mx = -__builtin_inff();
#pragma unroll
      for (int ni = 0; ni < 4; ++ni) {
        const int kvg = kv0 + (ni << 4) + c16;
        float v = sacc[ni][j] * 0.08838834764831845f;
        v = (kvg <= qg) ? v : -__builtin_inff();
        sacc[ni][j] = v;
        mx = fmaxf(mx, v);
      }
      mx = fmaxf(mx, __shfl_xor(mx, 1));
      mx = fmaxf(mx, __shfl_xor(mx, 2));
      mx = fmaxf(mx, __shfl_xor(mx, 4));
      mx = fmaxf(mx, __shfl_xor(mx, 8));
      const float mnew = fmaxf(mrow[j], mx);
      const float alpha = __expf(mrow[j] - mnew);
      mrow[j] = mnew;
      float rs = 0.f;
#pragma unroll
      for (int ni = 0; ni < 4; ++ni) {
        const float p = __expf(sacc[ni][j] - mnew);
        sacc[ni][j] = p;
        rs += p;
      }
      rs += __shfl_xor(rs, 1);
      rs += __shfl_xor(rs, 2);
      rs += __shfl_xor(rs, 4);
      rs += __shfl_xor(rs, 8);
      lsum[j] = lsum[j] * alpha + rs;
#pragma unroll
      for (int dn = 0; dn < 8; ++dn) oacc[dn][j] *= alpha;
    }
    __syncthreads();   // prior PV reads of Pl are done
    // P (C-layout) -> LDS, XOR-swizzled rows to kill b128-read bank conflicts
#pragma unroll
    for (int ni = 0; ni < 4; ++ni)
#pragma unroll
      for (int j = 0; j < 4; ++j) {
        const int row = (hi << 2) + j;
        int byt = (row << 7) + (((ni << 4) + c16) << 1);
        byt ^= (row & 7) << 4;
        *(u16*)(pw + byt) = f2h(sacc[ni][j]);
      }
    __syncthreads();   // P visible
    // PV: A = P (from LDS, transposed view), B = V^T rows (contiguous 16B)
#pragma unroll
    for (int kc = 0; kc < 2; ++kc) {
      int rb = (c16 << 7) + (kc << 6) + (hi << 4);
      rb ^= (c16 & 7) << 4;
      const f16x8 pa = *reinterpret_cast<const f16x8*>(pw + rb);
#pragma unroll
      for (int dn = 0; dn < 8; ++dn) {
        const f16x8 vbf = *reinterpret_cast<const f16x8*>(
            Vt + vb0 + (size_t)((dn << 4) + c16) * S_ + kv0 + (kc << 5) + (hi << 3));
        oacc[dn] = __builtin_amdgcn_mfma_f32_16x16x32_f16(pa, vbf, oacc[dn], 0, 0, 0);
      }
    }
  }
  // normalize + write H (f16)
  u16* Op = O + (size_t)(b * S_ + q0 + (wid << 4)) * DM_ + h * DH_;
#pragma unroll
  for (int j = 0; j < 4; ++j) {
    const float inv = 1.0f / lsum[j];
    const int r = (hi << 2) + j;
#pragma unroll
    for (int dn = 0; dn < 8; ++dn)
      Op[(size_t)r * DM_ + (dn << 4) + c16] = f2h(oacc[dn][j] * inv);
  }
}

extern "C" void kernel_launch(void* const* d_in, const int* in_sizes, int n_in,
                              void* d_out, int out_size, void* d_ws, size_t ws_size,
                              hipStream_t stream) {
  (void)in_sizes; (void)n_in; (void)out_size; (void)ws_size;
  const float* x  = (const float*)d_in[0];
  const float* wq = (const float*)d_in[1];
  const float* wk = (const float*)d_in[2];
  const float* wv = (const float*)d_in[3];
  const float* wo = (const float*)d_in[4];
  const int*   pos = (const int*)d_in[5];

  char* w = (char*)d_ws;
  u16* xh  = (u16*)(w + 0);           // 16 MB  (later reused as H buffer)
  u16* xl  = (u16*)(w + 16777216);
  u16* wqh = (u16*)(w + 33554432);
  u16* wql = (u16*)(w + 41943040);
  u16* wkh = (u16*)(w + 50331648);
  u16* wkl = (u16*)(w + 58720256);
  u16* wvh = (u16*)(w + 67108864);
  u16* woh = (u16*)(w + 75497472);
  u16* Qh  = (u16*)(w + 83886080);
  u16* Ql  = (u16*)(w + 100663296);
  u16* Kh  = (u16*)(w + 117440512);
  u16* Kl  = (u16*)(w + 134217728);
  u16* Vb  = (u16*)(w + 150994944);
  u16* Vt  = (u16*)(w + 167772160);
  float* ct = (float*)(w + 184549376);
  float* st = (float*)(w + 185073664);   // end: ~185.6 MB

  cvt_split_k<<<2048, 256, 0, stream>>>(x,  xh, xl, MROWS * DM_ / 4);
  cvt_split_k<<<1024, 256, 0, stream>>>(wq, wqh, wql, DM_ * DM_ / 4);
  cvt_split_k<<<1024, 256, 0, stream>>>(wk, wkh, wkl, DM_ * DM_ / 4);
  cvt_hi_k<<<1024, 256, 0, stream>>>(wv, wvh, DM_ * DM_ / 4);
  cvt_hi_k<<<1024, 256, 0, stream>>>(wo, woh, DM_ * DM_ / 4);
  rope_tab_k<<<S_, 64, 0, stream>>>(pos, ct, st);

  gemm_k<1><<<512, 256, 0, stream>>>(xh, xl, wqh, wql, Qh, Ql, ct, st, DM_, DM_);
  gemm_k<1><<<512, 256, 0, stream>>>(xh, xl, wkh, wkl, Kh, Kl, ct, st, DM_, DM_);
  gemm_k<0><<<512, 256, 0, stream>>>(xh, nullptr, wvh, nullptr, Vb, nullptr, nullptr, nullptr, DM_, DM_);
  transv_k<<<2048, 256, 0, stream>>>(Vb, Vt);
  attn_k<<<1024, 256, 0, stream>>>(Qh, Ql, Kh, Kl, Vt, xh /* H overwrites xh */);
  gemm_k<2><<<512, 256, 0, stream>>>(xh, nullptr, woh, nullptr, d_out, nullptr, nullptr, nullptr, DM_, DM_);
}

// Round 5
// 784.045 us; speedup vs baseline: 1.5137x; 1.5137x over previous
//
#include <hip/hip_runtime.h>
#include <stdint.h>

#define S_ 2048
#define H_ 16
#define DH_ 128
#define DM_ 2048
#define MROWS 4096   // B*S

typedef unsigned short u16;
typedef _Float16 f16x8 __attribute__((ext_vector_type(8)));
typedef float f32x4 __attribute__((ext_vector_type(4)));

__device__ __forceinline__ void gload16(const void* g, void* l) {
  __builtin_amdgcn_global_load_lds(
      (const __attribute__((address_space(1))) unsigned int*)g,
      (__attribute__((address_space(3))) unsigned int*)l, 16, 0, 0);
}

__device__ __forceinline__ u16 f2h(float f) {
  return __builtin_bit_cast(u16, (_Float16)f);
}

// ---------------- conversion kernels ----------------
__global__ void cvt_hi_k(const float* __restrict__ s, u16* __restrict__ dh, int n4) {
  int i = blockIdx.x * blockDim.x + threadIdx.x;
  const int st = gridDim.x * blockDim.x;
  for (; i < n4; i += st) {
    const float4 v = reinterpret_cast<const float4*>(s)[i];
    ushort4 h;
    h.x = f2h(v.x); h.y = f2h(v.y); h.z = f2h(v.z); h.w = f2h(v.w);
    reinterpret_cast<ushort4*>(dh)[i] = h;
  }
}

__global__ void cvt_split_k(const float* __restrict__ s, u16* __restrict__ dh,
                            u16* __restrict__ dl, int n4) {
  int i = blockIdx.x * blockDim.x + threadIdx.x;
  const int st = gridDim.x * blockDim.x;
  for (; i < n4; i += st) {
    const float4 v = reinterpret_cast<const float4*>(s)[i];
    ushort4 h, l;
    _Float16 b; float f;
    b = (_Float16)v.x; f = (float)b; h.x = __builtin_bit_cast(u16, b); l.x = f2h(v.x - f);
    b = (_Float16)v.y; f = (float)b; h.y = __builtin_bit_cast(u16, b); l.y = f2h(v.y - f);
    b = (_Float16)v.z; f = (float)b; h.z = __builtin_bit_cast(u16, b); l.z = f2h(v.z - f);
    b = (_Float16)v.w; f = (float)b; h.w = __builtin_bit_cast(u16, b); l.w = f2h(v.w - f);
    reinterpret_cast<ushort4*>(dh)[i] = h;
    reinterpret_cast<ushort4*>(dl)[i] = l;
  }
}

// cos/sin tables [S][64], f32, angle product done in f32 to mirror reference rounding
__global__ void rope_tab_k(const int* __restrict__ pos, float* __restrict__ ct,
                           float* __restrict__ st) {
  const int s = blockIdx.x, i = threadIdx.x;   // 64 threads
  const double invd = exp((double)i * (-9.210340371976184 / 64.0));
  const float a = (float)pos[s] * (float)invd;  // f32 RNE product like reference
  ct[(s << 6) + i] = (float)cos((double)a);
  st[(s << 6) + i] = (float)sin((double)a);
}

// ---------------- GEMM: out[m,n] = sum_k A[m,k]*B[n,k] ----------------
// MODE 0: plain f16 in -> f16 out (V proj)
// MODE 1: split f16 hi/lo in (3 mfma) -> RoPE epilogue (*qscale) -> dual f16 hi/lo out
// MODE 2: plain f16 in -> f32 out (O proj -> d_out)
template<int MODE>
__global__ __launch_bounds__(256)
void gemm_k(const u16* __restrict__ Ah, const u16* __restrict__ Al,
            const u16* __restrict__ Bh, const u16* __restrict__ Bl,
            void* __restrict__ C0, void* __restrict__ C1,
            const float* __restrict__ ct, const float* __restrict__ st,
            const int Nn, const int Kk, const float qscale) {
  constexpr int NB = (MODE == 1) ? 2 : 1;
  __shared__ __align__(16) u16 As[NB][4096];   // [128][32]
  __shared__ __align__(16) u16 Bs[NB][4096];
  const int tid = threadIdx.x;
  const int wid = tid >> 6, lane = tid & 63;
  const int c16 = lane & 15, hi = lane >> 4;
  const int nbn = Nn >> 7;
  const int bm = (int)blockIdx.x / nbn;
  const int bn = (int)blockIdx.x - bm * nbn;
  const int m0 = bm << 7, n0 = bn << 7;
  const int wm = (wid >> 1) << 6, wn = (wid & 1) << 6;

  f32x4 acc[4][4] = {};
  const int nk = Kk >> 5;
  for (int kt = 0; kt < nk; ++kt) {
    const int k0 = kt << 5;
    __syncthreads();
#pragma unroll
    for (int rep = 0; rep < 2; ++rep) {
      const int cw = wid + (rep << 2);
      const int c = (cw << 6) + lane;
      const size_t aoff = (size_t)(m0 + (c >> 2)) * Kk + k0 + ((c & 3) << 3);
      const size_t boff = (size_t)(n0 + (c >> 2)) * Kk + k0 + ((c & 3) << 3);
      gload16(Ah + aoff, &As[0][cw << 9]);
      gload16(Bh + boff, &Bs[0][cw << 9]);
      if constexpr (MODE == 1) {
        gload16(Al + aoff, &As[1][cw << 9]);
        gload16(Bl + boff, &Bs[1][cw << 9]);
      }
    }
    __syncthreads();
    f16x8 afh[4], bfh[4];
#pragma unroll
    for (int i = 0; i < 4; ++i) {
      afh[i] = *reinterpret_cast<const f16x8*>(&As[0][((wm + (i << 4) + c16) << 5) + (hi << 3)]);
      bfh[i] = *reinterpret_cast<const f16x8*>(&Bs[0][((wn + (i << 4) + c16) << 5) + (hi << 3)]);
    }
    if constexpr (MODE == 1) {
      f16x8 afl[4], bfl[4];
#pragma unroll
      for (int i = 0; i < 4; ++i) {
        afl[i] = *reinterpret_cast<const f16x8*>(&As[1][((wm + (i << 4) + c16) << 5) + (hi << 3)]);
        bfl[i] = *reinterpret_cast<const f16x8*>(&Bs[1][((wn + (i << 4) + c16) << 5) + (hi << 3)]);
      }
#pragma unroll
      for (int i = 0; i < 4; ++i)
#pragma unroll
        for (int j = 0; j < 4; ++j) {
          acc[i][j] = __builtin_amdgcn_mfma_f32_16x16x32_f16(afh[i], bfh[j], acc[i][j], 0, 0, 0);
          acc[i][j] = __builtin_amdgcn_mfma_f32_16x16x32_f16(afh[i], bfl[j], acc[i][j], 0, 0, 0);
          acc[i][j] = __builtin_amdgcn_mfma_f32_16x16x32_f16(afl[i], bfh[j], acc[i][j], 0, 0, 0);
        }
    } else {
#pragma unroll
      for (int i = 0; i < 4; ++i)
#pragma unroll
        for (int j = 0; j < 4; ++j)
          acc[i][j] = __builtin_amdgcn_mfma_f32_16x16x32_f16(afh[i], bfh[j], acc[i][j], 0, 0, 0);
    }
  }
  const int rbase = m0 + wm + (hi << 2);
  const int cbase = n0 + wn + c16;
  if constexpr (MODE == 2) {
    float* C = (float*)C0;
#pragma unroll
    for (int i = 0; i < 4; ++i)
#pragma unroll
      for (int j = 0; j < 4; ++j)
#pragma unroll
        for (int e = 0; e < 4; ++e)
          C[(size_t)(rbase + (i << 4) + e) * Nn + cbase + (j << 4)] = acc[i][j][e];
  } else if constexpr (MODE == 0) {
    u16* C = (u16*)C0;
#pragma unroll
    for (int i = 0; i < 4; ++i)
#pragma unroll
      for (int j = 0; j < 4; ++j)
#pragma unroll
        for (int e = 0; e < 4; ++e)
          C[(size_t)(rbase + (i << 4) + e) * Nn + cbase + (j << 4)] = f2h(acc[i][j][e]);
  } else {
    // MODE 1: RoPE (pair exchange across adjacent lanes) + hi/lo split write
    u16* Ch = (u16*)C0;
    u16* Cl = (u16*)C1;
    const bool even = ((c16 & 1) == 0);
#pragma unroll
    for (int j = 0; j < 4; ++j) {
      const int n = cbase + (j << 4);
      const int fi = (n & 127) >> 1;
#pragma unroll
      for (int i = 0; i < 4; ++i)
#pragma unroll
        for (int e = 0; e < 4; ++e) {
          const int r = rbase + (i << 4) + e;
          const int s = r & (S_ - 1);
          const float cz = ct[(s << 6) + fi];
          const float sz = st[(s << 6) + fi];
          const float v = acc[i][j][e];
          const float other = __shfl_xor(v, 1);
          const float res = (even ? (v * cz - other * sz) : (other * sz + v * cz)) * qscale;
          const _Float16 hb = (_Float16)res;
          const size_t off = (size_t)r * Nn + n;
          Ch[off] = __builtin_bit_cast(u16, hb);
          Cl[off] = f2h(res - (float)hb);
        }
    }
  }
}

// ---------------- V transpose: [B,S,H,Dh] -> [B,H,Dh,S] ----------------
__global__ __launch_bounds__(256)
void transv_k(const u16* __restrict__ V, u16* __restrict__ Vt) {
  __shared__ u16 tile[64][65];
  const int bid = blockIdx.x;          // B*H*32*2 = 2048
  const int dblk = bid & 1;
  const int sblk = (bid >> 1) & 31;
  const int bh = bid >> 6;             // 0..31
  const int b = bh >> 4, h = bh & 15;
  const int s0 = sblk << 6, d0 = dblk << 6;
  const int col = threadIdx.x & 63, rb = threadIdx.x >> 6;
#pragma unroll
  for (int i = 0; i < 16; ++i) {
    const int r = (i << 2) + rb;
    tile[r][col] = V[(size_t)(b * S_ + s0 + r) * DM_ + h * DH_ + d0 + col];
  }
  __syncthreads();
#pragma unroll
  for (int i = 0; i < 16; ++i) {
    const int d = (i << 2) + rb;
    Vt[(size_t)(bh * DH_ + d0 + d) * S_ + s0 + col] = tile[col][d];
  }
}

// ---------------- flash attention, causal, split-f16 QK^T ----------------
// LPT-balanced grid: qt = 31 - (bid>>5) so heavy blocks dispatch first.
// K tile (hi+lo) staged in LDS via global_load_lds with pre-swizzled source.
__global__ __launch_bounds__(256, 4)
void attn_k(const u16* __restrict__ Qh, const u16* __restrict__ Ql,
            const u16* __restrict__ Kh, const u16* __restrict__ Kl,
            const u16* __restrict__ Vt, u16* __restrict__ O) {
  __shared__ __align__(16) u16 Ks[2][64][128];  // 32 KB, granule ^= (row&7) swizzle
  __shared__ __align__(16) u16 Pl[4][1024];     // per-wave 16x64 P tile, XOR-swizzled
  const int bid = blockIdx.x;                   // 1024
  const int qt = 31 - (bid >> 5);
  const int bh = bid & 31;
  const int b = bh >> 4, h = bh & 15;
  const int q0 = qt << 6;
  const int tid = threadIdx.x;
  const int wid = tid >> 6, lane = tid & 63;
  const int c16 = lane & 15, hi = lane >> 4;

  const size_t qoff = (size_t)(b * S_ + q0 + (wid << 4) + c16) * DM_ + h * DH_;
  f16x8 qfh[4], qfl[4];
#pragma unroll
  for (int dc = 0; dc < 4; ++dc) {
    qfh[dc] = *reinterpret_cast<const f16x8*>(Qh + qoff + (dc << 5) + (hi << 3));
    qfl[dc] = *reinterpret_cast<const f16x8*>(Ql + qoff + (dc << 5) + (hi << 3));
  }

  // staging: granule g = it*256 + tid (16B each); 2048 granules = 32KB.
  // part = g>>10 (hi/lo), r = (g>>4)&63, gi = g&15; source granule pre-swizzled gi^(r&7).
  int srcoff[4];
#pragma unroll
  for (int it = 0; it < 4; ++it) {
    const int g = (it << 8) + tid;
    const int r = (g >> 4) & 63, gi = g & 15;
    srcoff[it] = r * DM_ + ((gi ^ (r & 7)) << 3);   // element offset within K-tile slab
  }
  u16* ksp = &Ks[0][0][0];

  float mrow[4], lsum[4];
#pragma unroll
  for (int j = 0; j < 4; ++j) { mrow[j] = -__builtin_inff(); lsum[j] = 0.f; }
  f32x4 oacc[8] = {};

  const size_t kvb = (size_t)(b * S_) * DM_ + h * DH_;
  const size_t vb0 = (size_t)bh * DH_ * S_;
  char* pw = (char*)&Pl[wid][0];

  for (int kt = 0; kt <= qt; ++kt) {
    const int kv0 = kt << 6;
    __syncthreads();                       // all waves done reading Ks of prev tile
    const size_t tb = kvb + (size_t)kv0 * DM_;
#pragma unroll
    for (int it = 0; it < 4; ++it) {
      gload16(Kh + tb + srcoff[it], ksp + (((it << 8) + (wid << 6)) << 3));
      gload16(Kl + tb + srcoff[it], ksp + 8192 + (((it << 8) + (wid << 6)) << 3));
    }
    asm volatile("s_waitcnt vmcnt(0)" ::: "memory");
    __syncthreads();                       // staged K visible to all waves

    f32x4 sacc[4] = {};
#pragma unroll
    for (int ni = 0; ni < 4; ++ni) {
      const int r = (ni << 4) + c16;
      const int rx = r & 7;
      const u16* krow = ksp + r * 128;
#pragma unroll
      for (int dc = 0; dc < 4; ++dc) {
        const int gsw = ((((dc << 2) + hi) ^ rx) << 3);
        const f16x8 kfh = *reinterpret_cast<const f16x8*>(krow + gsw);
        const f16x8 kfl = *reinterpret_cast<const f16x8*>(krow + 8192 + gsw);
        sacc[ni] = __builtin_amdgcn_mfma_f32_16x16x32_f16(qfh[dc], kfh, sacc[ni], 0, 0, 0);
        sacc[ni] = __builtin_amdgcn_mfma_f32_16x16x32_f16(qfh[dc], kfl, sacc[ni], 0, 0, 0);
        sacc[ni] = __builtin_amdgcn_mfma_f32_16x16x32_f16(qfl[dc], kfh, sacc[ni], 0, 0, 0);
      }
    }
    if (kt == qt) {                        // causal mask only on the diagonal tile
#pragma unroll
      for (int ni = 0; ni < 4; ++ni) {
        const int kvg = kv0 + (ni << 4) + c16;
#pragma unroll
        for (int j = 0; j < 4; ++j) {
          const int qg = q0 + (wid << 4) + (hi << 2) + j;
          if (kvg > qg) sacc[ni][j] = -__builtin_inff();
        }
      }
    }
    // online softmax (rows live in 16-lane groups); Q pre-scaled by 1/sqrt(dh)
#pragma unroll
    for (int j = 0; j < 4; ++j) {
      float mx = fmaxf(fmaxf(sacc[0][j], sacc[1][j]), fmaxf(sacc[2][j], sacc[3][j]));
      mx = fmaxf(mx, __shfl_xor(mx, 1));
      mx = fmaxf(mx, __shfl_xor(mx, 2));
      mx = fmaxf(mx, __shfl_xor(mx, 4));
      mx = fmaxf(mx, __shfl_xor(mx, 8));
      const float mnew = fmaxf(mrow[j], mx);
      const float alpha = __expf(mrow[j] - mnew);
      mrow[j] = mnew;
      float rs = 0.f;
#pragma unroll
      for (int ni = 0; ni < 4; ++ni) {
        const float p = __expf(sacc[ni][j] - mnew);
        sacc[ni][j] = p;
        rs += p;
      }
      rs += __shfl_xor(rs, 1);
      rs += __shfl_xor(rs, 2);
      rs += __shfl_xor(rs, 4);
      rs += __shfl_xor(rs, 8);
      lsum[j] = lsum[j] * alpha + rs;
#pragma unroll
      for (int dn = 0; dn < 8; ++dn) oacc[dn][j] *= alpha;
    }
    // P -> per-wave LDS (no block barrier needed: same-wave produce/consume)
#pragma unroll
    for (int ni = 0; ni < 4; ++ni)
#pragma unroll
      for (int j = 0; j < 4; ++j) {
        const int row = (hi << 2) + j;
        int byt = (row << 7) + (((ni << 4) + c16) << 1);
        byt ^= (row & 7) << 4;
        *(u16*)(pw + byt) = f2h(sacc[ni][j]);
      }
    asm volatile("s_waitcnt lgkmcnt(0)" ::: "memory");
    // PV: A = P (LDS, transposed view), B = V^T rows (contiguous 16B from global/L2)
#pragma unroll
    for (int kc = 0; kc < 2; ++kc) {
      int rb = (c16 << 7) + (kc << 6) + (hi << 4);
      rb ^= (c16 & 7) << 4;
      const f16x8 pa = *reinterpret_cast<const f16x8*>(pw + rb);
#pragma unroll
      for (int dn = 0; dn < 8; ++dn) {
        const f16x8 vbf = *reinterpret_cast<const f16x8*>(
            Vt + vb0 + (size_t)((dn << 4) + c16) * S_ + kv0 + (kc << 5) + (hi << 3));
        oacc[dn] = __builtin_amdgcn_mfma_f32_16x16x32_f16(pa, vbf, oacc[dn], 0, 0, 0);
      }
    }
  }
  // normalize + write H (f16)
  u16* Op = O + (size_t)(b * S_ + q0 + (wid << 4)) * DM_ + h * DH_;
#pragma unroll
  for (int j = 0; j < 4; ++j) {
    const float inv = 1.0f / lsum[j];
    const int r = (hi << 2) + j;
#pragma unroll
    for (int dn = 0; dn < 8; ++dn)
      Op[(size_t)r * DM_ + (dn << 4) + c16] = f2h(oacc[dn][j] * inv);
  }
}

extern "C" void kernel_launch(void* const* d_in, const int* in_sizes, int n_in,
                              void* d_out, int out_size, void* d_ws, size_t ws_size,
                              hipStream_t stream) {
  (void)in_sizes; (void)n_in; (void)out_size; (void)ws_size;
  const float* x  = (const float*)d_in[0];
  const float* wq = (const float*)d_in[1];
  const float* wk = (const float*)d_in[2];
  const float* wv = (const float*)d_in[3];
  const float* wo = (const float*)d_in[4];
  const int*   pos = (const int*)d_in[5];

  char* w = (char*)d_ws;
  u16* xh  = (u16*)(w + 0);           // 16 MB  (later reused as H buffer)
  u16* xl  = (u16*)(w + 16777216);
  u16* wqh = (u16*)(w + 33554432);
  u16* wql = (u16*)(w + 41943040);
  u16* wkh = (u16*)(w + 50331648);
  u16* wkl = (u16*)(w + 58720256);
  u16* wvh = (u16*)(w + 67108864);
  u16* woh = (u16*)(w + 75497472);
  u16* Qh  = (u16*)(w + 83886080);
  u16* Ql  = (u16*)(w + 100663296);
  u16* Kh  = (u16*)(w + 117440512);
  u16* Kl  = (u16*)(w + 134217728);
  u16* Vb  = (u16*)(w + 150994944);
  u16* Vt  = (u16*)(w + 167772160);
  float* ct = (float*)(w + 184549376);
  float* st = (float*)(w + 185073664);   // end: ~185.6 MB

  cvt_split_k<<<2048, 256, 0, stream>>>(x,  xh, xl, MROWS * DM_ / 4);
  cvt_split_k<<<1024, 256, 0, stream>>>(wq, wqh, wql, DM_ * DM_ / 4);
  cvt_split_k<<<1024, 256, 0, stream>>>(wk, wkh, wkl, DM_ * DM_ / 4);
  cvt_hi_k<<<1024, 256, 0, stream>>>(wv, wvh, DM_ * DM_ / 4);
  cvt_hi_k<<<1024, 256, 0, stream>>>(wo, woh, DM_ * DM_ / 4);
  rope_tab_k<<<S_, 64, 0, stream>>>(pos, ct, st);

  const float qsc = 0.08838834764831845f;  // 1/sqrt(128), folded into Q
  gemm_k<1><<<512, 256, 0, stream>>>(xh, xl, wqh, wql, Qh, Ql, ct, st, DM_, DM_, qsc);
  gemm_k<1><<<512, 256, 0, stream>>>(xh, xl, wkh, wkl, Kh, Kl, ct, st, DM_, DM_, 1.0f);
  gemm_k<0><<<512, 256, 0, stream>>>(xh, nullptr, wvh, nullptr, Vb, nullptr, nullptr, nullptr, DM_, DM_, 1.0f);
  transv_k<<<2048, 256, 0, stream>>>(Vb, Vt);
  attn_k<<<1024, 256, 0, stream>>>(Qh, Ql, Kh, Kl, Vt, xh /* H overwrites xh */);
  gemm_k<2><<<512, 256, 0, stream>>>(xh, nullptr, woh, nullptr, d_out, nullptr, nullptr, nullptr, DM_, DM_, 1.0f);
}

// Round 6
// 731.888 us; speedup vs baseline: 1.6216x; 1.0713x over previous
//
#include <hip/hip_runtime.h>
#include <stdint.h>

#define S_ 2048
#define H_ 16
#define DH_ 128
#define DM_ 2048
#define MROWS 4096   // B*S

typedef unsigned short u16;
typedef _Float16 f16x8 __attribute__((ext_vector_type(8)));
typedef float f32x4 __attribute__((ext_vector_type(4)));

__device__ __forceinline__ void gload16(const void* g, void* l) {
  __builtin_amdgcn_global_load_lds(
      (const __attribute__((address_space(1))) unsigned int*)g,
      (__attribute__((address_space(3))) unsigned int*)l, 16, 0, 0);
}

__device__ __forceinline__ u16 f2h(float f) {
  return __builtin_bit_cast(u16, (_Float16)f);
}

// ---------------- conversion kernels ----------------
__global__ void cvt_hi_k(const float* __restrict__ s, u16* __restrict__ dh, int n4) {
  int i = blockIdx.x * blockDim.x + threadIdx.x;
  const int st = gridDim.x * blockDim.x;
  for (; i < n4; i += st) {
    const float4 v = reinterpret_cast<const float4*>(s)[i];
    ushort4 h;
    h.x = f2h(v.x); h.y = f2h(v.y); h.z = f2h(v.z); h.w = f2h(v.w);
    reinterpret_cast<ushort4*>(dh)[i] = h;
  }
}

__global__ void cvt_split_k(const float* __restrict__ s, u16* __restrict__ dh,
                            u16* __restrict__ dl, int n4) {
  int i = blockIdx.x * blockDim.x + threadIdx.x;
  const int st = gridDim.x * blockDim.x;
  for (; i < n4; i += st) {
    const float4 v = reinterpret_cast<const float4*>(s)[i];
    ushort4 h, l;
    _Float16 b; float f;
    b = (_Float16)v.x; f = (float)b; h.x = __builtin_bit_cast(u16, b); l.x = f2h(v.x - f);
    b = (_Float16)v.y; f = (float)b; h.y = __builtin_bit_cast(u16, b); l.y = f2h(v.y - f);
    b = (_Float16)v.z; f = (float)b; h.z = __builtin_bit_cast(u16, b); l.z = f2h(v.z - f);
    b = (_Float16)v.w; f = (float)b; h.w = __builtin_bit_cast(u16, b); l.w = f2h(v.w - f);
    reinterpret_cast<ushort4*>(dh)[i] = h;
    reinterpret_cast<ushort4*>(dl)[i] = l;
  }
}

// cos/sin tables [S][64], f32, angle product done in f32 to mirror reference rounding
__global__ void rope_tab_k(const int* __restrict__ pos, float* __restrict__ ct,
                           float* __restrict__ st) {
  const int s = blockIdx.x, i = threadIdx.x;   // 64 threads
  const double invd = exp((double)i * (-9.210340371976184 / 64.0));
  const float a = (float)pos[s] * (float)invd;  // f32 RNE product like reference
  ct[(s << 6) + i] = (float)cos((double)a);
  st[(s << 6) + i] = (float)sin((double)a);
}

// ---------------- GEMM: out[m,n] = sum_k A[m,k]*B[n,k] ----------------
// MODE 0: plain f16 in -> f16 out (V proj)
// MODE 1: split f16 hi/lo in (3 mfma) -> RoPE epilogue (*qscale) -> dual f16 hi/lo out
// MODE 2: plain f16 in -> f32 out (O proj -> d_out)
template<int MODE>
__global__ __launch_bounds__(256)
void gemm_k(const u16* __restrict__ Ah, const u16* __restrict__ Al,
            const u16* __restrict__ Bh, const u16* __restrict__ Bl,
            void* __restrict__ C0, void* __restrict__ C1,
            const float* __restrict__ ct, const float* __restrict__ st,
            const int Nn, const int Kk, const float qscale) {
  constexpr int NB = (MODE == 1) ? 2 : 1;
  __shared__ __align__(16) u16 As[NB][4096];   // [128][32]
  __shared__ __align__(16) u16 Bs[NB][4096];
  const int tid = threadIdx.x;
  const int wid = tid >> 6, lane = tid & 63;
  const int c16 = lane & 15, hi = lane >> 4;
  const int nbn = Nn >> 7;
  const int bm = (int)blockIdx.x / nbn;
  const int bn = (int)blockIdx.x - bm * nbn;
  const int m0 = bm << 7, n0 = bn << 7;
  const int wm = (wid >> 1) << 6, wn = (wid & 1) << 6;

  f32x4 acc[4][4] = {};
  const int nk = Kk >> 5;
  for (int kt = 0; kt < nk; ++kt) {
    const int k0 = kt << 5;
    __syncthreads();
#pragma unroll
    for (int rep = 0; rep < 2; ++rep) {
      const int cw = wid + (rep << 2);
      const int c = (cw << 6) + lane;
      const size_t aoff = (size_t)(m0 + (c >> 2)) * Kk + k0 + ((c & 3) << 3);
      const size_t boff = (size_t)(n0 + (c >> 2)) * Kk + k0 + ((c & 3) << 3);
      gload16(Ah + aoff, &As[0][cw << 9]);
      gload16(Bh + boff, &Bs[0][cw << 9]);
      if constexpr (MODE == 1) {
        gload16(Al + aoff, &As[1][cw << 9]);
        gload16(Bl + boff, &Bs[1][cw << 9]);
      }
    }
    __syncthreads();
    f16x8 afh[4], bfh[4];
#pragma unroll
    for (int i = 0; i < 4; ++i) {
      afh[i] = *reinterpret_cast<const f16x8*>(&As[0][((wm + (i << 4) + c16) << 5) + (hi << 3)]);
      bfh[i] = *reinterpret_cast<const f16x8*>(&Bs[0][((wn + (i << 4) + c16) << 5) + (hi << 3)]);
    }
    if constexpr (MODE == 1) {
      f16x8 afl[4], bfl[4];
#pragma unroll
      for (int i = 0; i < 4; ++i) {
        afl[i] = *reinterpret_cast<const f16x8*>(&As[1][((wm + (i << 4) + c16) << 5) + (hi << 3)]);
        bfl[i] = *reinterpret_cast<const f16x8*>(&Bs[1][((wn + (i << 4) + c16) << 5) + (hi << 3)]);
      }
#pragma unroll
      for (int i = 0; i < 4; ++i)
#pragma unroll
        for (int j = 0; j < 4; ++j) {
          acc[i][j] = __builtin_amdgcn_mfma_f32_16x16x32_f16(afh[i], bfh[j], acc[i][j], 0, 0, 0);
          acc[i][j] = __builtin_amdgcn_mfma_f32_16x16x32_f16(afh[i], bfl[j], acc[i][j], 0, 0, 0);
          acc[i][j] = __builtin_amdgcn_mfma_f32_16x16x32_f16(afl[i], bfh[j], acc[i][j], 0, 0, 0);
        }
    } else {
#pragma unroll
      for (int i = 0; i < 4; ++i)
#pragma unroll
        for (int j = 0; j < 4; ++j)
          acc[i][j] = __builtin_amdgcn_mfma_f32_16x16x32_f16(afh[i], bfh[j], acc[i][j], 0, 0, 0);
    }
  }
  const int rbase = m0 + wm + (hi << 2);
  const int cbase = n0 + wn + c16;
  if constexpr (MODE == 2) {
    float* C = (float*)C0;
#pragma unroll
    for (int i = 0; i < 4; ++i)
#pragma unroll
      for (int j = 0; j < 4; ++j)
#pragma unroll
        for (int e = 0; e < 4; ++e)
          C[(size_t)(rbase + (i << 4) + e) * Nn + cbase + (j << 4)] = acc[i][j][e];
  } else if constexpr (MODE == 0) {
    u16* C = (u16*)C0;
#pragma unroll
    for (int i = 0; i < 4; ++i)
#pragma unroll
      for (int j = 0; j < 4; ++j)
#pragma unroll
        for (int e = 0; e < 4; ++e)
          C[(size_t)(rbase + (i << 4) + e) * Nn + cbase + (j << 4)] = f2h(acc[i][j][e]);
  } else {
    // MODE 1: RoPE (pair exchange across adjacent lanes) + hi/lo split write
    u16* Ch = (u16*)C0;
    u16* Cl = (u16*)C1;
    const bool even = ((c16 & 1) == 0);
#pragma unroll
    for (int j = 0; j < 4; ++j) {
      const int n = cbase + (j << 4);
      const int fi = (n & 127) >> 1;
#pragma unroll
      for (int i = 0; i < 4; ++i)
#pragma unroll
        for (int e = 0; e < 4; ++e) {
          const int r = rbase + (i << 4) + e;
          const int s = r & (S_ - 1);
          const float cz = ct[(s << 6) + fi];
          const float sz = st[(s << 6) + fi];
          const float v = acc[i][j][e];
          const float other = __shfl_xor(v, 1);
          const float res = (even ? (v * cz - other * sz) : (other * sz + v * cz)) * qscale;
          const _Float16 hb = (_Float16)res;
          const size_t off = (size_t)r * Nn + n;
          Ch[off] = __builtin_bit_cast(u16, hb);
          Cl[off] = f2h(res - (float)hb);
        }
    }
  }
}

// ---------------- V transpose: [B,S,H,Dh] -> [B,H,Dh,S] ----------------
__global__ __launch_bounds__(256)
void transv_k(const u16* __restrict__ V, u16* __restrict__ Vt) {
  __shared__ u16 tile[64][65];
  const int bid = blockIdx.x;          // B*H*32*2 = 2048
  const int dblk = bid & 1;
  const int sblk = (bid >> 1) & 31;
  const int bh = bid >> 6;             // 0..31
  const int b = bh >> 4, h = bh & 15;
  const int s0 = sblk << 6, d0 = dblk << 6;
  const int col = threadIdx.x & 63, rb = threadIdx.x >> 6;
#pragma unroll
  for (int i = 0; i < 16; ++i) {
    const int r = (i << 2) + rb;
    tile[r][col] = V[(size_t)(b * S_ + s0 + r) * DM_ + h * DH_ + d0 + col];
  }
  __syncthreads();
#pragma unroll
  for (int i = 0; i < 16; ++i) {
    const int d = (i << 2) + rb;
    Vt[(size_t)(bh * DH_ + d0 + d) * S_ + s0 + col] = tile[col][d];
  }
}

// ---------------- flash attention, causal, split-f16 QK^T ----------------
// Balanced pairing: each block does q-tiles {31-p, p} = exactly 33 kv-tile units.
// 512 blocks, all resident (2/CU). Double-buffered K staging: stage(kt+1) issued
// before QK(kt); single vmcnt(0)+barrier per tile, latency hidden under compute.
__global__ __launch_bounds__(256, 2)
void attn_k(const u16* __restrict__ Qh, const u16* __restrict__ Ql,
            const u16* __restrict__ Kh, const u16* __restrict__ Kl,
            const u16* __restrict__ Vt, u16* __restrict__ O) {
  __shared__ __align__(16) u16 Ks[2][16384];  // 2 bufs x {16KB hi | 16KB lo}, swizzled
  __shared__ __align__(16) u16 Pl[4][1024];   // per-wave 16x64 P tile, XOR-swizzled
  const int bid = blockIdx.x;                 // 512
  // bh-clustered IDs: bid%8 = bh&7 so each XCD's resident blocks share 4 K/V slabs
  const int bh = (bid & 7) | (((bid >> 7) & 3) << 3);
  const int p  = (bid >> 3) & 15;             // pair index 0..15
  const int b = bh >> 4, h = bh & 15;
  const int tid = threadIdx.x;
  const int wid = tid >> 6, lane = tid & 63;
  const int c16 = lane & 15, hi = lane >> 4;

  // staging: granule g = it*256 + tid (16B each); 1024 granules = 16KB per part.
  // r = (g>>4)&63, gi = g&15; source granule pre-swizzled gi^(r&7) (matches read XOR).
  int srcoff[4];
#pragma unroll
  for (int it = 0; it < 4; ++it) {
    const int g = (it << 8) + tid;
    const int r = (g >> 4) & 63, gi = g & 15;
    srcoff[it] = r * DM_ + ((gi ^ (r & 7)) << 3);
  }

  const size_t kvb = (size_t)(b * S_) * DM_ + h * DH_;
  const size_t vb0 = (size_t)bh * DH_ * S_;
  char* pw = (char*)&Pl[wid][0];
  int cur = 0;

  for (int half = 0; half < 2; ++half) {
    const int qt = half ? p : (31 - p);      // heavy tile first
    const int q0 = qt << 6;

    const size_t qoff = (size_t)(b * S_ + q0 + (wid << 4) + c16) * DM_ + h * DH_;
    f16x8 qfh[4], qfl[4];
#pragma unroll
    for (int dc = 0; dc < 4; ++dc) {
      qfh[dc] = *reinterpret_cast<const f16x8*>(Qh + qoff + (dc << 5) + (hi << 3));
      qfl[dc] = *reinterpret_cast<const f16x8*>(Ql + qoff + (dc << 5) + (hi << 3));
    }

    float mrow[4], lsum[4];
#pragma unroll
    for (int j = 0; j < 4; ++j) { mrow[j] = -__builtin_inff(); lsum[j] = 0.f; }
    f32x4 oacc[8] = {};

    // prologue: stage tile 0 into Ks[cur]
    {
      const size_t tb = kvb;
      u16* bb = &Ks[cur][0];
#pragma unroll
      for (int it = 0; it < 4; ++it) {
        gload16(Kh + tb + srcoff[it], bb + (((it << 8) + (wid << 6)) << 3));
        gload16(Kl + tb + srcoff[it], bb + 8192 + (((it << 8) + (wid << 6)) << 3));
      }
    }
    asm volatile("s_waitcnt vmcnt(0)" ::: "memory");
    __syncthreads();

    for (int kt = 0; kt <= qt; ++kt) {
      const int kv0 = kt << 6;
      // issue next tile's stage into the other buffer (no reader conflict)
      if (kt < qt) {
        const size_t tb = kvb + (size_t)(kv0 + 64) * DM_;
        u16* bb = &Ks[cur ^ 1][0];
#pragma unroll
        for (int it = 0; it < 4; ++it) {
          gload16(Kh + tb + srcoff[it], bb + (((it << 8) + (wid << 6)) << 3));
          gload16(Kl + tb + srcoff[it], bb + 8192 + (((it << 8) + (wid << 6)) << 3));
        }
      }

      const u16* kb = &Ks[cur][0];
      f32x4 sacc[4] = {};
      __builtin_amdgcn_s_setprio(1);
#pragma unroll
      for (int ni = 0; ni < 4; ++ni) {
        const int r = (ni << 4) + c16;
        const int rx = r & 7;
        const u16* krow = kb + r * 128;
#pragma unroll
        for (int dc = 0; dc < 4; ++dc) {
          const int gsw = ((((dc << 2) + hi) ^ rx) << 3);
          const f16x8 kfh = *reinterpret_cast<const f16x8*>(krow + gsw);
          const f16x8 kfl = *reinterpret_cast<const f16x8*>(krow + 8192 + gsw);
          sacc[ni] = __builtin_amdgcn_mfma_f32_16x16x32_f16(qfh[dc], kfh, sacc[ni], 0, 0, 0);
          sacc[ni] = __builtin_amdgcn_mfma_f32_16x16x32_f16(qfh[dc], kfl, sacc[ni], 0, 0, 0);
          sacc[ni] = __builtin_amdgcn_mfma_f32_16x16x32_f16(qfl[dc], kfh, sacc[ni], 0, 0, 0);
        }
      }
      __builtin_amdgcn_s_setprio(0);

      if (kt == qt) {                        // causal mask only on the diagonal tile
#pragma unroll
        for (int ni = 0; ni < 4; ++ni) {
          const int kvg = kv0 + (ni << 4) + c16;
#pragma unroll
          for (int j = 0; j < 4; ++j) {
            const int qg = q0 + (wid << 4) + (hi << 2) + j;
            if (kvg > qg) sacc[ni][j] = -__builtin_inff();
          }
        }
      }
      // online softmax (rows live in 16-lane groups); Q pre-scaled by 1/sqrt(dh)
#pragma unroll
      for (int j = 0; j < 4; ++j) {
        float mx = fmaxf(fmaxf(sacc[0][j], sacc[1][j]), fmaxf(sacc[2][j], sacc[3][j]));
        mx = fmaxf(mx, __shfl_xor(mx, 1));
        mx = fmaxf(mx, __shfl_xor(mx, 2));
        mx = fmaxf(mx, __shfl_xor(mx, 4));
        mx = fmaxf(mx, __shfl_xor(mx, 8));
        const float mnew = fmaxf(mrow[j], mx);
        const float alpha = __expf(mrow[j] - mnew);
        mrow[j] = mnew;
        float rs = 0.f;
#pragma unroll
        for (int ni = 0; ni < 4; ++ni) {
          const float pv = __expf(sacc[ni][j] - mnew);
          sacc[ni][j] = pv;
          rs += pv;
        }
        rs += __shfl_xor(rs, 1);
        rs += __shfl_xor(rs, 2);
        rs += __shfl_xor(rs, 4);
        rs += __shfl_xor(rs, 8);
        lsum[j] = lsum[j] * alpha + rs;
#pragma unroll
        for (int dn = 0; dn < 8; ++dn) oacc[dn][j] *= alpha;
      }
      // P -> per-wave LDS (same-wave produce/consume; no block barrier)
#pragma unroll
      for (int ni = 0; ni < 4; ++ni)
#pragma unroll
        for (int j = 0; j < 4; ++j) {
          const int row = (hi << 2) + j;
          int byt = (row << 7) + (((ni << 4) + c16) << 1);
          byt ^= (row & 7) << 4;
          *(u16*)(pw + byt) = f2h(sacc[ni][j]);
        }
      asm volatile("s_waitcnt lgkmcnt(0)" ::: "memory");
      // PV: A = P (LDS, transposed view), B = V^T rows (contiguous 16B from L2)
#pragma unroll
      for (int kc = 0; kc < 2; ++kc) {
        int rb = (c16 << 7) + (kc << 6) + (hi << 4);
        rb ^= (c16 & 7) << 4;
        const f16x8 pa = *reinterpret_cast<const f16x8*>(pw + rb);
#pragma unroll
        for (int dn = 0; dn < 8; ++dn) {
          const f16x8 vbf = *reinterpret_cast<const f16x8*>(
              Vt + vb0 + (size_t)((dn << 4) + c16) * S_ + kv0 + (kc << 5) + (hi << 3));
          oacc[dn] = __builtin_amdgcn_mfma_f32_16x16x32_f16(pa, vbf, oacc[dn], 0, 0, 0);
        }
      }
      // next tile's staged K has had the whole tile to land; one barrier per tile
      asm volatile("s_waitcnt vmcnt(0)" ::: "memory");
      __syncthreads();
      cur ^= 1;
    }
    // normalize + write H (f16) for this q-tile
    u16* Op = O + (size_t)(b * S_ + q0 + (wid << 4)) * DM_ + h * DH_;
#pragma unroll
    for (int j = 0; j < 4; ++j) {
      const float inv = 1.0f / lsum[j];
      const int r = (hi << 2) + j;
#pragma unroll
      for (int dn = 0; dn < 8; ++dn)
        Op[(size_t)r * DM_ + (dn << 4) + c16] = f2h(oacc[dn][j] * inv);
    }
  }
}

extern "C" void kernel_launch(void* const* d_in, const int* in_sizes, int n_in,
                              void* d_out, int out_size, void* d_ws, size_t ws_size,
                              hipStream_t stream) {
  (void)in_sizes; (void)n_in; (void)out_size; (void)ws_size;
  const float* x  = (const float*)d_in[0];
  const float* wq = (const float*)d_in[1];
  const float* wk = (const float*)d_in[2];
  const float* wv = (const float*)d_in[3];
  const float* wo = (const float*)d_in[4];
  const int*   pos = (const int*)d_in[5];

  char* w = (char*)d_ws;
  u16* xh  = (u16*)(w + 0);           // 16 MB  (later reused as H buffer)
  u16* xl  = (u16*)(w + 16777216);
  u16* wqh = (u16*)(w + 33554432);
  u16* wql = (u16*)(w + 41943040);
  u16* wkh = (u16*)(w + 50331648);
  u16* wkl = (u16*)(w + 58720256);
  u16* wvh = (u16*)(w + 67108864);
  u16* woh = (u16*)(w + 75497472);
  u16* Qh  = (u16*)(w + 83886080);
  u16* Ql  = (u16*)(w + 100663296);
  u16* Kh  = (u16*)(w + 117440512);
  u16* Kl  = (u16*)(w + 134217728);
  u16* Vb  = (u16*)(w + 150994944);
  u16* Vt  = (u16*)(w + 167772160);
  float* ct = (float*)(w + 184549376);
  float* st = (float*)(w + 185073664);   // end: ~185.6 MB

  cvt_split_k<<<2048, 256, 0, stream>>>(x,  xh, xl, MROWS * DM_ / 4);
  cvt_split_k<<<1024, 256, 0, stream>>>(wq, wqh, wql, DM_ * DM_ / 4);
  cvt_split_k<<<1024, 256, 0, stream>>>(wk, wkh, wkl, DM_ * DM_ / 4);
  cvt_hi_k<<<1024, 256, 0, stream>>>(wv, wvh, DM_ * DM_ / 4);
  cvt_hi_k<<<1024, 256, 0, stream>>>(wo, woh, DM_ * DM_ / 4);
  rope_tab_k<<<S_, 64, 0, stream>>>(pos, ct, st);

  const float qsc = 0.08838834764831845f;  // 1/sqrt(128), folded into Q
  gemm_k<1><<<512, 256, 0, stream>>>(xh, xl, wqh, wql, Qh, Ql, ct, st, DM_, DM_, qsc);
  gemm_k<1><<<512, 256, 0, stream>>>(xh, xl, wkh, wkl, Kh, Kl, ct, st, DM_, DM_, 1.0f);
  gemm_k<0><<<512, 256, 0, stream>>>(xh, nullptr, wvh, nullptr, Vb, nullptr, nullptr, nullptr, DM_, DM_, 1.0f);
  transv_k<<<2048, 256, 0, stream>>>(Vb, Vt);
  attn_k<<<512, 256, 0, stream>>>(Qh, Ql, Kh, Kl, Vt, xh /* H overwrites xh */);
  gemm_k<2><<<512, 256, 0, stream>>>(xh, nullptr, woh, nullptr, d_out, nullptr, nullptr, nullptr, DM_, DM_, 1.0f);
}

// Round 7
// 708.179 us; speedup vs baseline: 1.6759x; 1.0335x over previous
//
#include <hip/hip_runtime.h>
#include <stdint.h>

#define S_ 2048
#define H_ 16
#define DH_ 128
#define DM_ 2048
#define MROWS 4096   // B*S

typedef unsigned short u16;
typedef _Float16 f16x8 __attribute__((ext_vector_type(8)));
typedef float f32x4 __attribute__((ext_vector_type(4)));

__device__ __forceinline__ void gload16(const void* g, void* l) {
  __builtin_amdgcn_global_load_lds(
      (const __attribute__((address_space(1))) unsigned int*)g,
      (__attribute__((address_space(3))) unsigned int*)l, 16, 0, 0);
}

__device__ __forceinline__ u16 f2h(float f) {
  return __builtin_bit_cast(u16, (_Float16)f);
}

// ---------------- conversion kernels ----------------
__global__ void cvt_hi_k(const float* __restrict__ s, u16* __restrict__ dh, int n4) {
  int i = blockIdx.x * blockDim.x + threadIdx.x;
  const int st = gridDim.x * blockDim.x;
  for (; i < n4; i += st) {
    const float4 v = reinterpret_cast<const float4*>(s)[i];
    ushort4 h;
    h.x = f2h(v.x); h.y = f2h(v.y); h.z = f2h(v.z); h.w = f2h(v.w);
    reinterpret_cast<ushort4*>(dh)[i] = h;
  }
}

__global__ void cvt_split_k(const float* __restrict__ s, u16* __restrict__ dh,
                            u16* __restrict__ dl, int n4) {
  int i = blockIdx.x * blockDim.x + threadIdx.x;
  const int st = gridDim.x * blockDim.x;
  for (; i < n4; i += st) {
    const float4 v = reinterpret_cast<const float4*>(s)[i];
    ushort4 h, l;
    _Float16 b; float f;
    b = (_Float16)v.x; f = (float)b; h.x = __builtin_bit_cast(u16, b); l.x = f2h(v.x - f);
    b = (_Float16)v.y; f = (float)b; h.y = __builtin_bit_cast(u16, b); l.y = f2h(v.y - f);
    b = (_Float16)v.z; f = (float)b; h.z = __builtin_bit_cast(u16, b); l.z = f2h(v.z - f);
    b = (_Float16)v.w; f = (float)b; h.w = __builtin_bit_cast(u16, b); l.w = f2h(v.w - f);
    reinterpret_cast<ushort4*>(dh)[i] = h;
    reinterpret_cast<ushort4*>(dl)[i] = l;
  }
}

// cos/sin tables [S][64], f32, angle product done in f32 to mirror reference rounding
__global__ void rope_tab_k(const int* __restrict__ pos, float* __restrict__ ct,
                           float* __restrict__ st) {
  const int s = blockIdx.x, i = threadIdx.x;   // 64 threads
  const double invd = exp((double)i * (-9.210340371976184 / 64.0));
  const float a = (float)pos[s] * (float)invd;  // f32 RNE product like reference
  ct[(s << 6) + i] = (float)cos((double)a);
  st[(s << 6) + i] = (float)sin((double)a);
}

// ---------------- fused Q+K projection GEMM, split f16 hi/lo, RoPE epilogue ----
// Grid 1024: logical g = bijective XCD swizzle; bm=g>>5 (M=4096), bn=g&31 (N=4096).
// bn<16 -> Q (W=wq, out Qh/Ql, *qscale); bn>=16 -> K (W=wk, out Kh/Kl).
// Double-buffered LDS staging, ONE barrier per K-step (stage k+1 before compute k).
__global__ __launch_bounds__(256, 2)
void qkgemm_k(const u16* __restrict__ xh, const u16* __restrict__ xl,
              const u16* __restrict__ wqh, const u16* __restrict__ wql,
              const u16* __restrict__ wkh, const u16* __restrict__ wkl,
              u16* __restrict__ Qh, u16* __restrict__ Ql,
              u16* __restrict__ Kh, u16* __restrict__ Kl,
              const float* __restrict__ ct, const float* __restrict__ st) {
  __shared__ __align__(16) u16 As[2][2][4096];   // [buf][hi/lo][128x32]
  __shared__ __align__(16) u16 Bs[2][2][4096];
  const int tid = threadIdx.x;
  const int wid = tid >> 6, lane = tid & 63;
  const int c16 = lane & 15, hi = lane >> 4;
  const int orig = blockIdx.x;                   // 1024
  const int g = ((orig & 7) << 7) + (orig >> 3); // 128 blocks per XCD, contiguous g
  const int bm = g >> 5, bn = g & 31;
  const int m0 = bm << 7;
  const int nfull = bn << 7;
  const bool isK = (nfull >= 2048);
  const int n0 = nfull & 2047;
  const u16* Bh = isK ? wkh : wqh;
  const u16* Bl = isK ? wkl : wql;
  u16* Ch = isK ? Kh : Qh;
  u16* Cl = isK ? Kl : Ql;
  const float qscale = isK ? 1.0f : 0.08838834764831845f;
  const int wm = (wid >> 1) << 6, wn = (wid & 1) << 6;

  f32x4 acc[4][4] = {};
  int buf = 0;

  auto stage = [&](int kt, int b) {
    const int k0 = kt << 5;
#pragma unroll
    for (int rep = 0; rep < 2; ++rep) {
      const int cw = wid + (rep << 2);
      const int c = (cw << 6) + lane;
      const size_t aoff = (size_t)(m0 + (c >> 2)) * DM_ + k0 + ((c & 3) << 3);
      const size_t boff = (size_t)(n0 + (c >> 2)) * DM_ + k0 + ((c & 3) << 3);
      gload16(xh + aoff, &As[b][0][cw << 9]);
      gload16(xl + aoff, &As[b][1][cw << 9]);
      gload16(Bh + boff, &Bs[b][0][cw << 9]);
      gload16(Bl + boff, &Bs[b][1][cw << 9]);
    }
  };

  stage(0, 0);
  asm volatile("s_waitcnt vmcnt(0)" ::: "memory");
  __syncthreads();

  for (int kt = 0; kt < 64; ++kt) {
    if (kt < 63) stage(kt + 1, buf ^ 1);
    f16x8 afh[4], bfh[4], afl[4], bfl[4];
#pragma unroll
    for (int i = 0; i < 4; ++i) {
      const int ar = ((wm + (i << 4) + c16) << 5) + (hi << 3);
      const int br = ((wn + (i << 4) + c16) << 5) + (hi << 3);
      afh[i] = *reinterpret_cast<const f16x8*>(&As[buf][0][ar]);
      afl[i] = *reinterpret_cast<const f16x8*>(&As[buf][1][ar]);
      bfh[i] = *reinterpret_cast<const f16x8*>(&Bs[buf][0][br]);
      bfl[i] = *reinterpret_cast<const f16x8*>(&Bs[buf][1][br]);
    }
#pragma unroll
    for (int i = 0; i < 4; ++i)
#pragma unroll
      for (int j = 0; j < 4; ++j) {
        acc[i][j] = __builtin_amdgcn_mfma_f32_16x16x32_f16(afh[i], bfh[j], acc[i][j], 0, 0, 0);
        acc[i][j] = __builtin_amdgcn_mfma_f32_16x16x32_f16(afh[i], bfl[j], acc[i][j], 0, 0, 0);
        acc[i][j] = __builtin_amdgcn_mfma_f32_16x16x32_f16(afl[i], bfh[j], acc[i][j], 0, 0, 0);
      }
    asm volatile("s_waitcnt vmcnt(0)" ::: "memory");
    __syncthreads();
    buf ^= 1;
  }

  // RoPE epilogue (pair exchange across adjacent lanes) + hi/lo split write
  const int rbase = m0 + wm + (hi << 2);
  const int cbase = n0 + wn + c16;
  const bool even = ((c16 & 1) == 0);
#pragma unroll
  for (int j = 0; j < 4; ++j) {
    const int n = cbase + (j << 4);
    const int fi = (n & 127) >> 1;
#pragma unroll
    for (int i = 0; i < 4; ++i)
#pragma unroll
      for (int e = 0; e < 4; ++e) {
        const int r = rbase + (i << 4) + e;
        const int s = r & (S_ - 1);
        const float cz = ct[(s << 6) + fi];
        const float sz = st[(s << 6) + fi];
        const float v = acc[i][j][e];
        const float other = __shfl_xor(v, 1);
        const float res = (even ? (v * cz - other * sz) : (other * sz + v * cz)) * qscale;
        const _Float16 hb = (_Float16)res;
        const size_t off = (size_t)r * DM_ + n;
        Ch[off] = __builtin_bit_cast(u16, hb);
        Cl[off] = f2h(res - (float)hb);
      }
  }
}

// ---------------- plain f16 GEMM (V proj: MODE 0 -> f16; O proj: MODE 2 -> f32) --
// Same double-buffered single-barrier K-loop + XCD swizzle. Grid 512.
template<int MODE>
__global__ __launch_bounds__(256, 3)
void gemm2_k(const u16* __restrict__ Ah, const u16* __restrict__ Bh,
             void* __restrict__ C0) {
  __shared__ __align__(16) u16 As[2][4096];
  __shared__ __align__(16) u16 Bs[2][4096];
  const int tid = threadIdx.x;
  const int wid = tid >> 6, lane = tid & 63;
  const int c16 = lane & 15, hi = lane >> 4;
  const int orig = blockIdx.x;                  // 512
  const int g = ((orig & 7) << 6) + (orig >> 3);
  const int bm = g >> 4, bn = g & 15;
  const int m0 = bm << 7, n0 = bn << 7;
  const int wm = (wid >> 1) << 6, wn = (wid & 1) << 6;

  f32x4 acc[4][4] = {};
  int buf = 0;

  auto stage = [&](int kt, int b) {
    const int k0 = kt << 5;
#pragma unroll
    for (int rep = 0; rep < 2; ++rep) {
      const int cw = wid + (rep << 2);
      const int c = (cw << 6) + lane;
      const size_t aoff = (size_t)(m0 + (c >> 2)) * DM_ + k0 + ((c & 3) << 3);
      const size_t boff = (size_t)(n0 + (c >> 2)) * DM_ + k0 + ((c & 3) << 3);
      gload16(Ah + aoff, &As[b][cw << 9]);
      gload16(Bh + boff, &Bs[b][cw << 9]);
    }
  };

  stage(0, 0);
  asm volatile("s_waitcnt vmcnt(0)" ::: "memory");
  __syncthreads();

  for (int kt = 0; kt < 64; ++kt) {
    if (kt < 63) stage(kt + 1, buf ^ 1);
    f16x8 afh[4], bfh[4];
#pragma unroll
    for (int i = 0; i < 4; ++i) {
      afh[i] = *reinterpret_cast<const f16x8*>(&As[buf][((wm + (i << 4) + c16) << 5) + (hi << 3)]);
      bfh[i] = *reinterpret_cast<const f16x8*>(&Bs[buf][((wn + (i << 4) + c16) << 5) + (hi << 3)]);
    }
#pragma unroll
    for (int i = 0; i < 4; ++i)
#pragma unroll
      for (int j = 0; j < 4; ++j)
        acc[i][j] = __builtin_amdgcn_mfma_f32_16x16x32_f16(afh[i], bfh[j], acc[i][j], 0, 0, 0);
    asm volatile("s_waitcnt vmcnt(0)" ::: "memory");
    __syncthreads();
    buf ^= 1;
  }

  const int rbase = m0 + wm + (hi << 2);
  const int cbase = n0 + wn + c16;
  if constexpr (MODE == 2) {
    float* C = (float*)C0;
#pragma unroll
    for (int i = 0; i < 4; ++i)
#pragma unroll
      for (int j = 0; j < 4; ++j)
#pragma unroll
        for (int e = 0; e < 4; ++e)
          C[(size_t)(rbase + (i << 4) + e) * DM_ + cbase + (j << 4)] = acc[i][j][e];
  } else {
    u16* C = (u16*)C0;
#pragma unroll
    for (int i = 0; i < 4; ++i)
#pragma unroll
      for (int j = 0; j < 4; ++j)
#pragma unroll
        for (int e = 0; e < 4; ++e)
          C[(size_t)(rbase + (i << 4) + e) * DM_ + cbase + (j << 4)] = f2h(acc[i][j][e]);
  }
}

// ---------------- V transpose: [B,S,H,Dh] -> [B,H,Dh,S] ----------------
__global__ __launch_bounds__(256)
void transv_k(const u16* __restrict__ V, u16* __restrict__ Vt) {
  __shared__ u16 tile[64][65];
  const int bid = blockIdx.x;          // B*H*32*2 = 2048
  const int dblk = bid & 1;
  const int sblk = (bid >> 1) & 31;
  const int bh = bid >> 6;             // 0..31
  const int b = bh >> 4, h = bh & 15;
  const int s0 = sblk << 6, d0 = dblk << 6;
  const int col = threadIdx.x & 63, rb = threadIdx.x >> 6;
#pragma unroll
  for (int i = 0; i < 16; ++i) {
    const int r = (i << 2) + rb;
    tile[r][col] = V[(size_t)(b * S_ + s0 + r) * DM_ + h * DH_ + d0 + col];
  }
  __syncthreads();
#pragma unroll
  for (int i = 0; i < 16; ++i) {
    const int d = (i << 2) + rb;
    Vt[(size_t)(bh * DH_ + d0 + d) * S_ + s0 + col] = tile[col][d];
  }
}

// ---------------- flash attention, causal, split-f16 QK^T ----------------
// Balanced pairing: each block does q-tiles {31-p, p} = exactly 33 kv-tile units.
// 512 blocks, all resident (2/CU). Double-buffered K staging: stage(kt+1) issued
// before QK(kt); single vmcnt(0)+barrier per tile, latency hidden under compute.
__global__ __launch_bounds__(256, 2)
void attn_k(const u16* __restrict__ Qh, const u16* __restrict__ Ql,
            const u16* __restrict__ Kh, const u16* __restrict__ Kl,
            const u16* __restrict__ Vt, u16* __restrict__ O) {
  __shared__ __align__(16) u16 Ks[2][16384];  // 2 bufs x {16KB hi | 16KB lo}, swizzled
  __shared__ __align__(16) u16 Pl[4][1024];   // per-wave 16x64 P tile, XOR-swizzled
  const int bid = blockIdx.x;                 // 512
  // bh-clustered IDs: bid%8 = bh&7 so each XCD's resident blocks share 4 K/V slabs
  const int bh = (bid & 7) | (((bid >> 7) & 3) << 3);
  const int p  = (bid >> 3) & 15;             // pair index 0..15
  const int b = bh >> 4, h = bh & 15;
  const int tid = threadIdx.x;
  const int wid = tid >> 6, lane = tid & 63;
  const int c16 = lane & 15, hi = lane >> 4;

  // staging: granule g = it*256 + tid (16B each); 1024 granules = 16KB per part.
  // r = (g>>4)&63, gi = g&15; source granule pre-swizzled gi^(r&7) (matches read XOR).
  int srcoff[4];
#pragma unroll
  for (int it = 0; it < 4; ++it) {
    const int g = (it << 8) + tid;
    const int r = (g >> 4) & 63, gi = g & 15;
    srcoff[it] = r * DM_ + ((gi ^ (r & 7)) << 3);
  }

  const size_t kvb = (size_t)(b * S_) * DM_ + h * DH_;
  const size_t vb0 = (size_t)bh * DH_ * S_;
  char* pw = (char*)&Pl[wid][0];
  int cur = 0;

  for (int half = 0; half < 2; ++half) {
    const int qt = half ? p : (31 - p);      // heavy tile first
    const int q0 = qt << 6;

    const size_t qoff = (size_t)(b * S_ + q0 + (wid << 4) + c16) * DM_ + h * DH_;
    f16x8 qfh[4], qfl[4];
#pragma unroll
    for (int dc = 0; dc < 4; ++dc) {
      qfh[dc] = *reinterpret_cast<const f16x8*>(Qh + qoff + (dc << 5) + (hi << 3));
      qfl[dc] = *reinterpret_cast<const f16x8*>(Ql + qoff + (dc << 5) + (hi << 3));
    }

    float mrow[4], lsum[4];
#pragma unroll
    for (int j = 0; j < 4; ++j) { mrow[j] = -__builtin_inff(); lsum[j] = 0.f; }
    f32x4 oacc[8] = {};

    // prologue: stage tile 0 into Ks[cur]
    {
      const size_t tb = kvb;
      u16* bb = &Ks[cur][0];
#pragma unroll
      for (int it = 0; it < 4; ++it) {
        gload16(Kh + tb + srcoff[it], bb + (((it << 8) + (wid << 6)) << 3));
        gload16(Kl + tb + srcoff[it], bb + 8192 + (((it << 8) + (wid << 6)) << 3));
      }
    }
    asm volatile("s_waitcnt vmcnt(0)" ::: "memory");
    __syncthreads();

    for (int kt = 0; kt <= qt; ++kt) {
      const int kv0 = kt << 6;
      // issue next tile's stage into the other buffer (no reader conflict)
      if (kt < qt) {
        const size_t tb = kvb + (size_t)(kv0 + 64) * DM_;
        u16* bb = &Ks[cur ^ 1][0];
#pragma unroll
        for (int it = 0; it < 4; ++it) {
          gload16(Kh + tb + srcoff[it], bb + (((it << 8) + (wid << 6)) << 3));
          gload16(Kl + tb + srcoff[it], bb + 8192 + (((it << 8) + (wid << 6)) << 3));
        }
      }

      const u16* kb = &Ks[cur][0];
      f32x4 sacc[4] = {};
      __builtin_amdgcn_s_setprio(1);
#pragma unroll
      for (int ni = 0; ni < 4; ++ni) {
        const int r = (ni << 4) + c16;
        const int rx = r & 7;
        const u16* krow = kb + r * 128;
#pragma unroll
        for (int dc = 0; dc < 4; ++dc) {
          const int gsw = ((((dc << 2) + hi) ^ rx) << 3);
          const f16x8 kfh = *reinterpret_cast<const f16x8*>(krow + gsw);
          const f16x8 kfl = *reinterpret_cast<const f16x8*>(krow + 8192 + gsw);
          sacc[ni] = __builtin_amdgcn_mfma_f32_16x16x32_f16(qfh[dc], kfh, sacc[ni], 0, 0, 0);
          sacc[ni] = __builtin_amdgcn_mfma_f32_16x16x32_f16(qfh[dc], kfl, sacc[ni], 0, 0, 0);
          sacc[ni] = __builtin_amdgcn_mfma_f32_16x16x32_f16(qfl[dc], kfh, sacc[ni], 0, 0, 0);
        }
      }
      __builtin_amdgcn_s_setprio(0);

      if (kt == qt) {                        // causal mask only on the diagonal tile
#pragma unroll
        for (int ni = 0; ni < 4; ++ni) {
          const int kvg = kv0 + (ni << 4) + c16;
#pragma unroll
          for (int j = 0; j < 4; ++j) {
            const int qg = q0 + (wid << 4) + (hi << 2) + j;
            if (kvg > qg) sacc[ni][j] = -__builtin_inff();
          }
        }
      }
      // online softmax (rows live in 16-lane groups); Q pre-scaled by 1/sqrt(dh)
#pragma unroll
      for (int j = 0; j < 4; ++j) {
        float mx = fmaxf(fmaxf(sacc[0][j], sacc[1][j]), fmaxf(sacc[2][j], sacc[3][j]));
        mx = fmaxf(mx, __shfl_xor(mx, 1));
        mx = fmaxf(mx, __shfl_xor(mx, 2));
        mx = fmaxf(mx, __shfl_xor(mx, 4));
        mx = fmaxf(mx, __shfl_xor(mx, 8));
        const float mnew = fmaxf(mrow[j], mx);
        const float alpha = __expf(mrow[j] - mnew);
        mrow[j] = mnew;
        float rs = 0.f;
#pragma unroll
        for (int ni = 0; ni < 4; ++ni) {
          const float pv = __expf(sacc[ni][j] - mnew);
          sacc[ni][j] = pv;
          rs += pv;
        }
        rs += __shfl_xor(rs, 1);
        rs += __shfl_xor(rs, 2);
        rs += __shfl_xor(rs, 4);
        rs += __shfl_xor(rs, 8);
        lsum[j] = lsum[j] * alpha + rs;
#pragma unroll
        for (int dn = 0; dn < 8; ++dn) oacc[dn][j] *= alpha;
      }
      // P -> per-wave LDS (same-wave produce/consume; no block barrier)
#pragma unroll
      for (int ni = 0; ni < 4; ++ni)
#pragma unroll
        for (int j = 0; j < 4; ++j) {
          const int row = (hi << 2) + j;
          int byt = (row << 7) + (((ni << 4) + c16) << 1);
          byt ^= (row & 7) << 4;
          *(u16*)(pw + byt) = f2h(sacc[ni][j]);
        }
      asm volatile("s_waitcnt lgkmcnt(0)" ::: "memory");
      // PV: A = P (LDS, transposed view), B = V^T rows (contiguous 16B from L2)
#pragma unroll
      for (int kc = 0; kc < 2; ++kc) {
        int rb = (c16 << 7) + (kc << 6) + (hi << 4);
        rb ^= (c16 & 7) << 4;
        const f16x8 pa = *reinterpret_cast<const f16x8*>(pw + rb);
#pragma unroll
        for (int dn = 0; dn < 8; ++dn) {
          const f16x8 vbf = *reinterpret_cast<const f16x8*>(
              Vt + vb0 + (size_t)((dn << 4) + c16) * S_ + kv0 + (kc << 5) + (hi << 3));
          oacc[dn] = __builtin_amdgcn_mfma_f32_16x16x32_f16(pa, vbf, oacc[dn], 0, 0, 0);
        }
      }
      // next tile's staged K has had the whole tile to land; one barrier per tile
      asm volatile("s_waitcnt vmcnt(0)" ::: "memory");
      __syncthreads();
      cur ^= 1;
    }
    // normalize + write H (f16) for this q-tile
    u16* Op = O + (size_t)(b * S_ + q0 + (wid << 4)) * DM_ + h * DH_;
#pragma unroll
    for (int j = 0; j < 4; ++j) {
      const float inv = 1.0f / lsum[j];
      const int r = (hi << 2) + j;
#pragma unroll
      for (int dn = 0; dn < 8; ++dn)
        Op[(size_t)r * DM_ + (dn << 4) + c16] = f2h(oacc[dn][j] * inv);
    }
  }
}

extern "C" void kernel_launch(void* const* d_in, const int* in_sizes, int n_in,
                              void* d_out, int out_size, void* d_ws, size_t ws_size,
                              hipStream_t stream) {
  (void)in_sizes; (void)n_in; (void)out_size; (void)ws_size;
  const float* x  = (const float*)d_in[0];
  const float* wq = (const float*)d_in[1];
  const float* wk = (const float*)d_in[2];
  const float* wv = (const float*)d_in[3];
  const float* wo = (const float*)d_in[4];
  const int*   pos = (const int*)d_in[5];

  char* w = (char*)d_ws;
  u16* xh  = (u16*)(w + 0);           // 16 MB  (later reused as H buffer)
  u16* xl  = (u16*)(w + 16777216);
  u16* wqh = (u16*)(w + 33554432);
  u16* wql = (u16*)(w + 41943040);
  u16* wkh = (u16*)(w + 50331648);
  u16* wkl = (u16*)(w + 58720256);
  u16* wvh = (u16*)(w + 67108864);
  u16* woh = (u16*)(w + 75497472);
  u16* Qh  = (u16*)(w + 83886080);
  u16* Ql  = (u16*)(w + 100663296);
  u16* Kh  = (u16*)(w + 117440512);
  u16* Kl  = (u16*)(w + 134217728);
  u16* Vb  = (u16*)(w + 150994944);
  u16* Vt  = (u16*)(w + 167772160);
  float* ct = (float*)(w + 184549376);
  float* st = (float*)(w + 185073664);   // end: ~185.6 MB

  cvt_split_k<<<2048, 256, 0, stream>>>(x,  xh, xl, MROWS * DM_ / 4);
  cvt_split_k<<<1024, 256, 0, stream>>>(wq, wqh, wql, DM_ * DM_ / 4);
  cvt_split_k<<<1024, 256, 0, stream>>>(wk, wkh, wkl, DM_ * DM_ / 4);
  cvt_hi_k<<<1024, 256, 0, stream>>>(wv, wvh, DM_ * DM_ / 4);
  cvt_hi_k<<<1024, 256, 0, stream>>>(wo, woh, DM_ * DM_ / 4);
  rope_tab_k<<<S_, 64, 0, stream>>>(pos, ct, st);

  qkgemm_k<<<1024, 256, 0, stream>>>(xh, xl, wqh, wql, wkh, wkl,
                                     Qh, Ql, Kh, Kl, ct, st);
  gemm2_k<0><<<512, 256, 0, stream>>>(xh, wvh, Vb);
  transv_k<<<2048, 256, 0, stream>>>(Vb, Vt);
  attn_k<<<512, 256, 0, stream>>>(Qh, Ql, Kh, Kl, Vt, xh /* H overwrites xh */);
  gemm2_k<2><<<512, 256, 0, stream>>>(xh, woh, d_out);
}